// Round 9
// baseline (1174.195 us; speedup 1.0000x reference)
//
#include <hip/hip_runtime.h>
#include <hip/hip_bf16.h>
#include <math.h>

#define NN 15000
#define NE 60000
#define NB 512
#define NIF 15
#define EIF 5
#define EHID 128
#define NSTEP 6

typedef _Float16 half8 __attribute__((ext_vector_type(8)));
typedef float floatx4 __attribute__((ext_vector_type(4)));

typedef __attribute__((address_space(3))) _Float16 lds_f16;
typedef __attribute__((address_space(1))) const _Float16 glb_f16;

__device__ __forceinline__ void gload_lds16(const _Float16* g, _Float16* l) {
  __builtin_amdgcn_global_load_lds((glb_f16*)g, (lds_f16*)l, 16, 0, 0);
}

__device__ __forceinline__ float sigmoidf_(float x) { return 1.f / (1.f + expf(-x)); }

__global__ void k_sentinel(float* out) { out[0] = 1000.0f; }

// ---- fused setup: lin0 (+relu), degree, per-graph bounds ----
__global__ void k_setup(const float* __restrict__ x, const float* __restrict__ l0w,
                        const float* __restrict__ l0b, const int* __restrict__ tgt,
                        const int* __restrict__ batch, float* __restrict__ outv,
                        float* __restrict__ deg, int* __restrict__ gstart,
                        int* __restrict__ gend) {
  int idx = blockIdx.x * 256 + threadIdx.x;
  if (idx < NN * 64) {
    int n = idx >> 6, d = idx & 63;
    float s = l0b[d];
#pragma unroll
    for (int i = 0; i < NIF; ++i) s += x[n * NIF + i] * l0w[d * NIF + i];
    outv[idx] = fmaxf(s, 0.f);
  }
  if (idx < NE) atomicAdd(&deg[tgt[idx]], 1.0f);
  if (idx < NN) {
    int bb = batch[idx];
    atomicMin(&gstart[bb], idx);
    atomicMax(&gend[bb], idx + 1);
  }
}

// ---- fused pack ----
// w2q: idx<524288: j=idx&7, l15=(idx>>3)&15, q=(idx>>7)&3, og=(idx>>9)&1,
//   c=(idx>>10)&63, sb=idx>>16; hb=sb>>1, ob=sb&1; h=hb*32+q*8+j,
//   o=ob*32+og*16+l15, i=c; val=w2[(i*64+o)*128+h].
//   (per-split B fragments: split sb covers h-range 32, o-range 32, all 64 i)
// b2q (follows at 524288, 4096 vals): t: j,l15,q,og as above, c2=(t>>10)&1,
//   ob=(t>>11)&1; i=c2*32+q*8+j, o=ob*32+og*16+l15; val=b2[i*64+o].
// wgpk: 24576 f16 @528384: [(kind*2+cc)<4][o<192][r<32] (unchanged)
// wTih: 32768 f32, wThh: 16384 f32 (unchanged)
__global__ void k_packall(const float* __restrict__ w2, const float* __restrict__ b2,
                          const float* __restrict__ gwih, const float* __restrict__ gwhh,
                          const float* __restrict__ lwih, const float* __restrict__ lwhh,
                          _Float16* __restrict__ w2q, _Float16* __restrict__ wgpk,
                          float* __restrict__ wTih, float* __restrict__ wThh) {
  int idx = blockIdx.x * 256 + threadIdx.x;
  if (idx < 524288) {
    int j = idx & 7, l15 = (idx >> 3) & 15, q = (idx >> 7) & 3;
    int og = (idx >> 9) & 1, c = (idx >> 10) & 63, sb = idx >> 16;
    int hb = sb >> 1, ob = sb & 1;
    int h = hb * 32 + q * 8 + j;
    int o = ob * 32 + og * 16 + l15;
    w2q[idx] = (_Float16)w2[((size_t)(c * 64 + o)) * 128 + h];
  } else if (idx < 528384) {
    int t = idx - 524288;
    int j = t & 7, l15 = (t >> 3) & 15, q = (t >> 7) & 3;
    int og = (t >> 9) & 1, c2 = (t >> 10) & 1, ob = (t >> 11) & 1;
    int i = c2 * 32 + q * 8 + j;
    int o = ob * 32 + og * 16 + l15;
    w2q[idx] = (_Float16)b2[i * 64 + o];
  } else if (idx < 528384 + 24576) {
    int i2 = idx - 528384;
    int kc = i2 / 6144;          // (kind*2+cc)
    int rem = i2 % 6144;
    int o = rem >> 5, r = rem & 31;
    int kind = kc >> 1, cc = kc & 1;
    float v = kind ? gwhh[o * 64 + cc * 32 + r] : gwih[o * 64 + cc * 32 + r];
    wgpk[i2] = (_Float16)v;
  } else if (idx < 528384 + 24576 + 32768) {
    int i3 = idx - (528384 + 24576);
    int k = i3 >> 8, g = i3 & 255;
    wTih[i3] = lwih[g * 128 + k];
  } else if (idx < 528384 + 24576 + 32768 + 16384) {
    int i4 = idx - (528384 + 24576 + 32768);
    int k = i4 >> 8, g = i4 & 255;
    wThh[i4] = lwhh[g * 64 + k];
  }
}

// ---- fused message pass: B-RESIDENT, barrier-free K-loop ----
// R1-R8 lesson: every stage-per-K-step schedule pins MfmaUtil at ~25% (the
// 2-phase structural ceiling, m233/m230). This kernel removes main-loop sync
// entirely: 8-way K-split (hb<4: h-range 32; ob<2: o-range 32) makes the
// per-split B exactly 128 KB -> resident in LDS after a ONE-TIME DMA.
// Grid (32, 8) = 256 blocks = 1/CU @ 160.5 KB LDS. Each block grid-strides
// over ~15 groups of 128 edges; per group: stage os(64i)/hid(32h), barrier,
// then 64 chunks x 4 MFMA/wave with only per-wave ds_reads (1-chunk
// register prefetch) — no barriers, no vmcnt, no DMA. Atomics unchanged
// (each split writes its own 32 cols: 8x32 == 4x64). Bias handled by the
// hb==0 splits via 2 extra chunks with A=os.
__global__ __launch_bounds__(256, 1) void k_msg(
    const float* __restrict__ outv, const float* __restrict__ ea,
    const float* __restrict__ w1, const float* __restrict__ b1,
    const _Float16* __restrict__ w2q, const int* __restrict__ src,
    const int* __restrict__ tgt, float* __restrict__ agg) {
  __shared__ __align__(16) _Float16 bQ[65536];      // 128 KB resident split-B
  __shared__ __align__(16) _Float16 osL[128][72];   // 64 i + pad8 (144B rows)
  __shared__ __align__(16) _Float16 hidL[128][40];  // 32 h + pad8 (80B rows)
  __shared__ float w1L[192];                        // 32x5 w1 + 32 b1 (h-range)
  int tid = threadIdx.x;
  int bx = blockIdx.x;   // 0..31 edge-group stripe
  int sb = blockIdx.y;   // 0..7 split
  int hb = sb >> 1, ob = sb & 1;

  // one-time B stage: 32 DMA rounds x 256 thr x 16 B = 128 KB
  {
    const _Float16* gb = w2q + (size_t)sb * 65536 + tid * 8;
    _Float16* lb = bQ + tid * 8;
#pragma unroll
    for (int r = 0; r < 32; ++r)
      gload_lds16(gb + r * 2048, lb + r * 2048);
  }
  if (tid < 192)
    w1L[tid] = (tid < 160) ? w1[hb * 160 + tid] : b1[hb * 32 + tid - 160];

  int wv = tid >> 6, lane = tid & 63;
  int l15 = lane & 15, q = lane >> 4;
  int rbase = wv * 32 + l15;
  int el = tid >> 1, hf = tid & 1;
  const _Float16* b2q = w2q + 524288;
  const int fb = q * 128 + l15 * 8;  // frag base within a 1024-elem chunk

  __syncthreads();  // w1L visible; B DMA drained (one-time cost)

  for (int g = bx; g * 128 < NE; g += 32) {
    // ---- stage os (full 64 i) + hid (split's 32 h), 2 threads/edge ----
    int e = g * 128 + el;
    bool valid = e < NE;
    int s = valid ? src[e] : 0;
    const float4* op = (const float4*)(outv + (size_t)s * 64 + hf * 32);
#pragma unroll
    for (int pr = 0; pr < 4; ++pr) {
      float4 va = op[pr * 2 + 0];
      float4 vb = op[pr * 2 + 1];
      if (!valid) { va = vb = make_float4(0.f, 0.f, 0.f, 0.f); }
      half8 pk;
      pk[0] = (_Float16)va.x; pk[1] = (_Float16)va.y;
      pk[2] = (_Float16)va.z; pk[3] = (_Float16)va.w;
      pk[4] = (_Float16)vb.x; pk[5] = (_Float16)vb.y;
      pk[6] = (_Float16)vb.z; pk[7] = (_Float16)vb.w;
      *(half8*)&osL[el][hf * 32 + pr * 8] = pk;
    }
    {
      float eav[EIF];
#pragma unroll
      for (int i = 0; i < EIF; ++i) eav[i] = valid ? ea[e * EIF + i] : 0.f;
      _Float16 hreg[16];
#pragma unroll
      for (int k = 0; k < 16; ++k) {
        int hl = hf * 16 + k;
        float sum = w1L[160 + hl];
#pragma unroll
        for (int i = 0; i < EIF; ++i) sum += eav[i] * w1L[hl * EIF + i];
        hreg[k] = (_Float16)fmaxf(sum, 0.f);
      }
#pragma unroll
      for (int pk2 = 0; pk2 < 2; ++pk2) {
        half8 hv;
#pragma unroll
        for (int j = 0; j < 8; ++j) hv[j] = hreg[pk2 * 8 + j];
        *(half8*)&hidL[el][hf * 16 + pk2 * 8] = hv;
      }
    }
    __syncthreads();  // staging visible to all waves

    // ---- barrier-free K-loop: 64 chunks, 1-chunk register prefetch ----
    floatx4 acc[2][2];
#pragma unroll
    for (int m = 0; m < 2; ++m)
#pragma unroll
      for (int og = 0; og < 2; ++og) acc[m][og] = (floatx4){0.f, 0.f, 0.f, 0.f};

    half8 hidf0 = *(const half8*)&hidL[rbase][q * 8];
    half8 hidf1 = *(const half8*)&hidL[rbase + 16][q * 8];
    half8 frA0 = *(const half8*)&bQ[fb];
    half8 frA1 = *(const half8*)&bQ[512 + fb];
    _Float16 oa0 = osL[rbase][0];
    _Float16 oa1 = osL[rbase + 16][0];
#pragma unroll 4
    for (int c = 0; c < 64; ++c) {
      int cn = (c + 1) & 63;  // c=63 wraps to 0: in-bounds dummy prefetch
      half8 frB0 = *(const half8*)&bQ[cn * 1024 + fb];
      half8 frB1 = *(const half8*)&bQ[cn * 1024 + 512 + fb];
      _Float16 ob0 = osL[rbase][cn];
      _Float16 ob1 = osL[rbase + 16][cn];
      half8 osp0 = {oa0, oa0, oa0, oa0, oa0, oa0, oa0, oa0};
      half8 osp1 = {oa1, oa1, oa1, oa1, oa1, oa1, oa1, oa1};
      half8 af0 = hidf0 * osp0;
      half8 af1 = hidf1 * osp1;
      acc[0][0] = __builtin_amdgcn_mfma_f32_16x16x32_f16(af0, frA0, acc[0][0], 0, 0, 0);
      acc[1][0] = __builtin_amdgcn_mfma_f32_16x16x32_f16(af1, frA0, acc[1][0], 0, 0, 0);
      acc[0][1] = __builtin_amdgcn_mfma_f32_16x16x32_f16(af0, frA1, acc[0][1], 0, 0, 0);
      acc[1][1] = __builtin_amdgcn_mfma_f32_16x16x32_f16(af1, frA1, acc[1][1], 0, 0, 0);
      frA0 = frB0; frA1 = frB1; oa0 = ob0; oa1 = ob1;
    }

    if (hb == 0) {  // bias: A = os directly, K = i (2 chunks of 32)
#pragma unroll
      for (int c2 = 0; c2 < 2; ++c2) {
#pragma unroll
        for (int og = 0; og < 2; ++og) {
          half8 bf = *(const half8*)&b2q[((ob * 2 + c2) * 2 + og) * 512 + fb];
#pragma unroll
          for (int m = 0; m < 2; ++m) {
            half8 af = *(const half8*)&osL[rbase + m * 16][c2 * 32 + q * 8];
            acc[m][og] = __builtin_amdgcn_mfma_f32_16x16x32_f16(af, bf, acc[m][og], 0, 0, 0);
          }
        }
      }
    }

    // epilogue: C/D row=(lane>>4)*4+j (edge), col=lane&15 within o-half
#pragma unroll
    for (int m = 0; m < 2; ++m) {
      int erow = g * 128 + wv * 32 + m * 16 + q * 4;
#pragma unroll
      for (int j = 0; j < 4; ++j) {
        int ee = erow + j;
        if (ee < NE) {
          int t = tgt[ee];
          float* ap = agg + (size_t)t * 64 + ob * 32 + l15;
          atomicAdd(ap, acc[m][0][j]);
          atomicAdd(ap + 16, acc[m][1][j]);
        }
      }
    }
    __syncthreads();  // all waves done with osL/hidL before next stage
  }
}

// ---- GRU step via MFMA: gates = [m,h](f16) @ [Wih;Whh]^T; fused nonlinearity.
// 64 nodes/block, 4 waves; wave w owns gate cols {w*16..+16} of r,z,n tiles.
// Also zeroes agg in-place (after reading) for the next step's atomics.
__global__ __launch_bounds__(256, 2) void k_gru(
    float* __restrict__ agg, const float* __restrict__ deg,
    const float* __restrict__ convb, const _Float16* __restrict__ wgpk,
    const float* __restrict__ bih, const float* __restrict__ bhh,
    float* __restrict__ outv) {
  __shared__ __align__(16) _Float16 aL[64][136];  // K=128 + pad8
  __shared__ float hF[64][68];
  __shared__ float cbL[64];
  int tid = threadIdx.x;
  int n0 = blockIdx.x * 64;
  if (tid < 64) cbL[tid] = convb[tid];
  __syncthreads();

  int nl = tid >> 2, dq = (tid & 3) * 16;
  int n = n0 + nl;
  if (n < NN) {
    float dg = fmaxf(deg[n], 1.f);
    const float4* ap = (const float4*)(agg + (size_t)n * 64 + dq);
    const float4* hp = (const float4*)(outv + (size_t)n * 64 + dq);
    float4* az = (float4*)(agg + (size_t)n * 64 + dq);
#pragma unroll
    for (int t = 0; t < 4; ++t) {
      float4 a = ap[t];
      float4 h = hp[t];
      int d = dq + t * 4;
      aL[nl][d + 0] = (_Float16)fmaxf(a.x / dg + cbL[d + 0], 0.f);
      aL[nl][d + 1] = (_Float16)fmaxf(a.y / dg + cbL[d + 1], 0.f);
      aL[nl][d + 2] = (_Float16)fmaxf(a.z / dg + cbL[d + 2], 0.f);
      aL[nl][d + 3] = (_Float16)fmaxf(a.w / dg + cbL[d + 3], 0.f);
      aL[nl][64 + d + 0] = (_Float16)h.x;
      aL[nl][64 + d + 1] = (_Float16)h.y;
      aL[nl][64 + d + 2] = (_Float16)h.z;
      aL[nl][64 + d + 3] = (_Float16)h.w;
      hF[nl][d + 0] = h.x; hF[nl][d + 1] = h.y;
      hF[nl][d + 2] = h.z; hF[nl][d + 3] = h.w;
      az[t] = make_float4(0.f, 0.f, 0.f, 0.f);
    }
  } else {
#pragma unroll
    for (int t = 0; t < 4; ++t) {
      int d = dq + t * 4;
#pragma unroll
      for (int u = 0; u < 4; ++u) {
        aL[nl][d + u] = (_Float16)0.f;
        aL[nl][64 + d + u] = (_Float16)0.f;
        hF[nl][d + u] = 0.f;
      }
    }
  }
  __syncthreads();

  int wv = tid >> 6, lane = tid & 63, l15 = lane & 15, qd = lane >> 4;
  floatx4 acc[4][3][2];
#pragma unroll
  for (int mt = 0; mt < 4; ++mt)
#pragma unroll
    for (int tt = 0; tt < 3; ++tt)
#pragma unroll
      for (int kind = 0; kind < 2; ++kind) acc[mt][tt][kind] = (floatx4){0.f, 0.f, 0.f, 0.f};

#pragma unroll
  for (int kind = 0; kind < 2; ++kind) {
#pragma unroll
    for (int cc = 0; cc < 2; ++cc) {
      half8 af[4];
#pragma unroll
      for (int mt = 0; mt < 4; ++mt)
        af[mt] = *(const half8*)&aL[mt * 16 + l15][kind * 64 + cc * 32 + qd * 8];
#pragma unroll
      for (int tt = 0; tt < 3; ++tt) {
        int gb = (tt * 4 + wv) * 16;
        half8 bf = *(const half8*)&wgpk[((size_t)(kind * 2 + cc) * 192 + gb + l15) * 32 + qd * 8];
#pragma unroll
        for (int mt = 0; mt < 4; ++mt)
          acc[mt][tt][kind] = __builtin_amdgcn_mfma_f32_16x16x32_f16(af[mt], bf, acc[mt][tt][kind], 0, 0, 0);
      }
    }
  }

  int d = wv * 16 + l15;
  float bir = bih[d], bhr = bhh[d];
  float biz = bih[64 + d], bhz = bhh[64 + d];
  float bin = bih[128 + d], bhn = bhh[128 + d];
#pragma unroll
  for (int mt = 0; mt < 4; ++mt) {
#pragma unroll
    for (int j = 0; j < 4; ++j) {
      int nloc = mt * 16 + qd * 4 + j;
      int nn = n0 + nloc;
      if (nn < NN) {
        float ir = acc[mt][0][0][j] + bir, hr = acc[mt][0][1][j] + bhr;
        float iz = acc[mt][1][0][j] + biz, hz = acc[mt][1][1][j] + bhz;
        float in_ = acc[mt][2][0][j] + bin, hn = acc[mt][2][1][j] + bhn;
        float r = sigmoidf_(ir + hr);
        float z = sigmoidf_(iz + hz);
        float ng = tanhf(in_ + r * hn);
        float h = hF[nloc][d];
        outv[(size_t)nn * 64 + d] = (1.f - z) * ng + z * h;
      }
    }
  }
}

// ---- fully fused Set2Set (6 steps) + head, one block per graph ----
__global__ __launch_bounds__(256) void k_s2s(
    const float* __restrict__ outv, const int* __restrict__ gstart,
    const int* __restrict__ gend, const float* __restrict__ wTih,
    const float* __restrict__ wThh, const float* __restrict__ bih,
    const float* __restrict__ bhh, const float* __restrict__ l1w,
    const float* __restrict__ l1b, const float* __restrict__ l2w,
    const float* __restrict__ l2b, float* __restrict__ y) {
  __shared__ float qL[128], hlL[64], clL[64], gL[256];
  __shared__ float mxA[4], smA[4], accA[4][64], hidL[64];
  int b = blockIdx.x, tid = threadIdx.x, wv = tid >> 6, lane = tid & 63;
  int s0 = gstart[b], e0 = gend[b];
  if (s0 > e0) { s0 = 0; e0 = 0; }
  if (tid < 128) qL[tid] = 0.f;
  if (tid < 64) { hlL[tid] = 0.f; clL[tid] = 0.f; }
  __syncthreads();

  for (int step = 0; step < NSTEP; ++step) {
    {  // LSTM gates, one per thread (coalesced via transposed weights)
      int g = tid;
      float s = bih[g] + bhh[g];
      for (int k = 0; k < 128; ++k) s += qL[k] * wTih[k * 256 + g];
      for (int k = 0; k < 64; ++k) s += hlL[k] * wThh[k * 256 + g];
      gL[g] = s;
    }
    __syncthreads();
    if (tid < 64) {
      float ig = gL[tid], fg = gL[64 + tid], gg = gL[128 + tid], og = gL[192 + tid];
      float c = sigmoidf_(fg) * clL[tid] + sigmoidf_(ig) * tanhf(gg);
      clL[tid] = c;
      hlL[tid] = sigmoidf_(og) * tanhf(c);
    }
    __syncthreads();
    // attention: waves split nodes strided; two passes (max, then sum/acc)
    float hd = hlL[lane];
    float mxw = -1e30f;
    for (int nn = s0 + wv; nn < e0; nn += 4) {
      float v = outv[(size_t)nn * 64 + lane] * hd;
#pragma unroll
      for (int off = 32; off > 0; off >>= 1) v += __shfl_xor(v, off);
      mxw = fmaxf(mxw, v);
    }
    if (lane == 0) mxA[wv] = mxw;
    __syncthreads();
    float mx = fmaxf(fmaxf(mxA[0], mxA[1]), fmaxf(mxA[2], mxA[3]));
    float sm = 0.f, ac = 0.f;
    for (int nn = s0 + wv; nn < e0; nn += 4) {
      float o_nd = outv[(size_t)nn * 64 + lane];
      float v = o_nd * hd;
#pragma unroll
      for (int off = 32; off > 0; off >>= 1) v += __shfl_xor(v, off);
      float ex = expf(v - mx);
      sm += ex;
      ac += ex * o_nd;
    }
    if (lane == 0) smA[wv] = sm;
    accA[wv][lane] = ac;
    __syncthreads();
    if (tid < 64) {
      float den = smA[0] + smA[1] + smA[2] + smA[3] + 1e-16f;
      float rv = (accA[0][tid] + accA[1][tid] + accA[2][tid] + accA[3][tid]) / den;
      qL[tid] = hlL[tid];
      qL[64 + tid] = rv;
    }
    __syncthreads();
  }
  // head
  if (tid < 64) {
    float s = l1b[tid];
    for (int k = 0; k < 128; ++k) s += qL[k] * l1w[tid * 128 + k];
    hidL[tid] = fmaxf(s, 0.f);
  }
  __syncthreads();
  if (tid < 12) {
    float s = l2b[tid];
    for (int k = 0; k < 64; ++k) s += hidL[k] * l2w[tid * 64 + k];
    y[b * 12 + tid] = s;
  }
}

extern "C" void kernel_launch(void* const* d_in, const int* in_sizes, int n_in,
                              void* d_out, int out_size, void* d_ws, size_t ws_size,
                              hipStream_t stream) {
  const float* x = (const float*)d_in[0];
  const float* ea = (const float*)d_in[1];
  const int* eidx = (const int*)d_in[2];
  const int* batch = (const int*)d_in[3];
  const float* lin0_w = (const float*)d_in[4];
  const float* lin0_b = (const float*)d_in[5];
  const float* en_w1 = (const float*)d_in[6];
  const float* en_b1 = (const float*)d_in[7];
  const float* en_w2 = (const float*)d_in[8];
  const float* en_b2 = (const float*)d_in[9];
  const float* conv_b = (const float*)d_in[10];
  const float* gru_wih = (const float*)d_in[11];
  const float* gru_whh = (const float*)d_in[12];
  const float* gru_bih = (const float*)d_in[13];
  const float* gru_bhh = (const float*)d_in[14];
  const float* lstm_wih = (const float*)d_in[15];
  const float* lstm_whh = (const float*)d_in[16];
  const float* lstm_bih = (const float*)d_in[17];
  const float* lstm_bhh = (const float*)d_in[18];
  const float* lin1_w = (const float*)d_in[19];
  const float* lin1_b = (const float*)d_in[20];
  const float* lin2_w = (const float*)d_in[21];
  const float* lin2_b = (const float*)d_in[22];
  const int* srcp = eidx;
  const int* tgtp = eidx + NE;

  char* ws = (char*)d_ws;
  size_t off = 0;
  auto alloc = [&](size_t bytes) {
    char* p = ws + off;
    off += (bytes + 255) & ~(size_t)255;
    return p;
  };
  _Float16* w2q = (_Float16*)alloc((size_t)528384 * 2);  // w2q (1MB) + b2q (8KB)
  _Float16* wgpk = (_Float16*)alloc((size_t)24576 * 2);
  float* wTih = (float*)alloc((size_t)32768 * 4);
  float* wThh = (float*)alloc((size_t)16384 * 4);
  float* out = (float*)alloc((size_t)NN * 64 * 4);
  float* agg = (float*)alloc((size_t)NN * 64 * 4);
  float* deg = (float*)alloc((size_t)NN * 4);
  int* gstart = (int*)alloc((size_t)NB * 4);
  int* gend = (int*)alloc((size_t)NB * 4);
  if (off > ws_size) {
    k_sentinel<<<1, 1, 0, stream>>>((float*)d_out);
    return;
  }

  hipMemsetAsync(deg, 0, (size_t)NN * 4, stream);
  hipMemsetAsync(gstart, 0x7f, (size_t)NB * 4, stream);
  hipMemsetAsync(gend, 0, (size_t)NB * 4, stream);
  hipMemsetAsync(agg, 0, (size_t)NN * 64 * 4, stream);

  k_setup<<<(NN * 64 + 255) / 256, 256, 0, stream>>>(x, lin0_w, lin0_b, tgtp, batch,
                                                     out, deg, gstart, gend);
  k_packall<<<(528384 + 24576 + 32768 + 16384 + 255) / 256, 256, 0, stream>>>(
      en_w2, en_b2, gru_wih, gru_whh, lstm_wih, lstm_whh, w2q, wgpk, wTih, wThh);

  for (int step = 0; step < NSTEP; ++step) {
    k_msg<<<dim3(32, 8), 256, 0, stream>>>(out, ea, en_w1, en_b1,
                                           w2q, srcp, tgtp, agg);
    k_gru<<<(NN + 63) / 64, 256, 0, stream>>>(agg, deg, conv_b, wgpk, gru_bih,
                                              gru_bhh, out);
  }

  k_s2s<<<NB, 256, 0, stream>>>(out, gstart, gend, wTih, wThh, lstm_bih, lstm_bhh,
                                lin1_w, lin1_b, lin2_w, lin2_b, (float*)d_out);
}

// Round 10
// 744.154 us; speedup vs baseline: 1.5779x; 1.5779x over previous
//
#include <hip/hip_runtime.h>
#include <hip/hip_bf16.h>
#include <math.h>

#define NN 15000
#define NE 60000
#define NB 512
#define NIF 15
#define EIF 5
#define EHID 128
#define NSTEP 6
#define EPB 128   // edges per k_msg block (4 waves x 32 edges/wave)

typedef _Float16 half8 __attribute__((ext_vector_type(8)));
typedef float floatx4 __attribute__((ext_vector_type(4)));

typedef __attribute__((address_space(3))) _Float16 lds_f16;
typedef __attribute__((address_space(1))) const _Float16 glb_f16;

__device__ __forceinline__ void gload_lds16(const _Float16* g, _Float16* l) {
  __builtin_amdgcn_global_load_lds((glb_f16*)g, (lds_f16*)l, 16, 0, 0);
}

__device__ __forceinline__ float sigmoidf_(float x) { return 1.f / (1.f + expf(-x)); }

__global__ void k_sentinel(float* out) { out[0] = 1000.0f; }

// ---- fused init: lin0 (+relu), degree, graph bounds, ALL weight packs ----
// (merges R8's k_setup + k_packall: disjoint elementwise ranges, one launch)
// w2pp: idx<528384, layout [g<1032][o<64][j<8]; g<1024: k=g*8+j, i=k>>7, h=k&127,
//       val=w2[(i*64+o)*128+h]; g>=1024: i=(g-1024)*8+j, val=b2[i*64+o].
// wgpk: 24576 f16: [(kind*2+cc)<4][o<192][r<32], val=W[o][cc*32+r] (kind0=ih,1=hh)
// wTih: 32768 f32: [k<128][g<256] = lstm_wih[g*128+k]
// wThh: 16384 f32: [k<64][g<256]  = lstm_whh[g*64+k]
__global__ void k_init(const float* __restrict__ x, const float* __restrict__ l0w,
                       const float* __restrict__ l0b, const int* __restrict__ tgt,
                       const int* __restrict__ batch, float* __restrict__ outv,
                       float* __restrict__ deg, int* __restrict__ gstart,
                       int* __restrict__ gend,
                       const float* __restrict__ w2, const float* __restrict__ b2,
                       const float* __restrict__ gwih, const float* __restrict__ gwhh,
                       const float* __restrict__ lwih, const float* __restrict__ lwhh,
                       _Float16* __restrict__ w2pp, _Float16* __restrict__ wgpk,
                       float* __restrict__ wTih, float* __restrict__ wThh) {
  int idx = blockIdx.x * 256 + threadIdx.x;
  if (idx < NN * 64) {
    int n = idx >> 6, d = idx & 63;
    float s = l0b[d];
#pragma unroll
    for (int i = 0; i < NIF; ++i) s += x[n * NIF + i] * l0w[d * NIF + i];
    outv[idx] = fmaxf(s, 0.f);
  }
  if (idx < NE) atomicAdd(&deg[tgt[idx]], 1.0f);
  if (idx < NN) {
    int bb = batch[idx];
    atomicMin(&gstart[bb], idx);
    atomicMax(&gend[bb], idx + 1);
  }
  // ---- packs ----
  if (idx < 528384) {
    int g = idx >> 9;
    int r = idx & 511;
    int o = r >> 3, j = r & 7;
    float v;
    if (g < 1024) {
      int i = g >> 4;
      int h = ((g & 15) << 3) + j;
      v = w2[(size_t)(i * 64 + o) * 128 + h];
    } else {
      int i = ((g - 1024) << 3) + j;
      v = b2[i * 64 + o];
    }
    w2pp[idx] = (_Float16)v;
  } else if (idx < 528384 + 24576) {
    int i2 = idx - 528384;
    int kc = i2 / 6144;          // (kind*2+cc)
    int rem = i2 % 6144;
    int o = rem >> 5, r = rem & 31;
    int kind = kc >> 1, cc = kc & 1;
    float v = kind ? gwhh[o * 64 + cc * 32 + r] : gwih[o * 64 + cc * 32 + r];
    wgpk[i2] = (_Float16)v;
  } else if (idx < 528384 + 24576 + 32768) {
    int i3 = idx - (528384 + 24576);
    int k = i3 >> 8, g = i3 & 255;
    wTih[i3] = lwih[g * 128 + k];
  } else if (idx < 528384 + 24576 + 32768 + 16384) {
    int i4 = idx - (528384 + 24576 + 32768);
    int k = i4 >> 8, g = i4 & 255;
    wThh[i4] = lwhh[g * 64 + k];
  }
}

// ---- fused message pass, 4-way K-split, LDS-staged B, hidL/bS overlay ----
// R8's best-measured kernel (92.4 us, MfmaUtil 28, occ 40%), kept VERBATIM.
// R5/R6/R7/R9 bracket it as the local optimum: more sync = worse, fewer
// co-resident blocks = worse. blockIdx.y split: ib=y>>1 (i-range 32), hb=y&1
// (h-range 64); chunks c=(ib*32+il)*4+hb*2+hc + bias chunk on hb==0.
// hidL is DEAD after hidf regs -> B double-buffer overlays it; LDS 30.2K ->
// 5 blocks/CU (20 waves) hide the 2-phase barrier tax (m114 mechanism).
__global__ __launch_bounds__(256, 5) void k_msg(
    const float* __restrict__ outv, const float* __restrict__ ea,
    const float* __restrict__ w1, const float* __restrict__ b1,
    const _Float16* __restrict__ w2pp, const int* __restrict__ src,
    const int* __restrict__ tgt, float* __restrict__ agg) {
  __shared__ __align__(16) _Float16 hidL[EPB][72];  // h 64+pad8; REUSED as bS[2][4096]
  __shared__ __align__(16) _Float16 osL[EPB][40];   // i-range 32 + pad8
  __shared__ float w1L[384];                        // 64x5 w1 + 64 b1 (h-range)
  _Float16* const bSp = &hidL[0][0];                // overlay: 2 x 4096 f16 = 16 KB
  int tid = threadIdx.x;
  int e0 = blockIdx.x * EPB;
  int ib = blockIdx.y >> 1, hb = blockIdx.y & 1;
  const int cbase = ib * 128 + hb * 2;  // chunk(il,hc) = cbase + il*4 + hc

  for (int idx = tid; idx < 384; idx += 256)
    w1L[idx] = (idx < 320) ? w1[hb * 320 + idx] : b1[hb * 64 + idx - 320];

  // staging: 2 threads per edge, vectorized half8 LDS writes
  int el = tid >> 1, hf = tid & 1;
  int e = e0 + el;
  bool valid = e < NE;
  int s = valid ? src[e] : 0;
  const float4* op = (const float4*)(outv + (size_t)s * 64 + ib * 32);
  {
    float4 v0 = op[hf * 4 + 0];
    float4 v1 = op[hf * 4 + 1];
    float4 v2 = op[hf * 4 + 2];
    float4 v3 = op[hf * 4 + 3];
    if (!valid) {
      v0 = v1 = v2 = v3 = make_float4(0.f, 0.f, 0.f, 0.f);
    }
    half8 p0, p1;
    p0[0] = (_Float16)v0.x; p0[1] = (_Float16)v0.y;
    p0[2] = (_Float16)v0.z; p0[3] = (_Float16)v0.w;
    p0[4] = (_Float16)v1.x; p0[5] = (_Float16)v1.y;
    p0[6] = (_Float16)v1.z; p0[7] = (_Float16)v1.w;
    p1[0] = (_Float16)v2.x; p1[1] = (_Float16)v2.y;
    p1[2] = (_Float16)v2.z; p1[3] = (_Float16)v2.w;
    p1[4] = (_Float16)v3.x; p1[5] = (_Float16)v3.y;
    p1[6] = (_Float16)v3.z; p1[7] = (_Float16)v3.w;
    *(half8*)&osL[el][hf * 16 + 0] = p0;
    *(half8*)&osL[el][hf * 16 + 8] = p1;
  }
  float eav[EIF];
#pragma unroll
  for (int i = 0; i < EIF; ++i) eav[i] = valid ? ea[e * EIF + i] : 0.f;
  __syncthreads();  // w1L ready
  {
    _Float16 hreg[32];
#pragma unroll
    for (int k = 0; k < 32; ++k) {
      int hh = hf * 32 + k;
      float sum = w1L[320 + hh];
#pragma unroll
      for (int i = 0; i < EIF; ++i) sum += eav[i] * w1L[hh * EIF + i];
      hreg[k] = (_Float16)fmaxf(sum, 0.f);
    }
#pragma unroll
    for (int pk = 0; pk < 4; ++pk) {
      half8 hv;
#pragma unroll
      for (int j = 0; j < 8; ++j) hv[j] = hreg[pk * 8 + j];
      *(half8*)&hidL[el][hf * 32 + pk * 8] = hv;
    }
  }
  __syncthreads();  // osL/hidL ready

  int wv = tid >> 6, lane = tid & 63;
  int l15 = lane & 15, q = lane >> 4;
  int rbase = wv * 32 + l15;

  // loop-invariant hid A-frags -> registers; hidL is DEAD after this
  half8 hidf[2][2];
#pragma unroll
  for (int m = 0; m < 2; ++m)
#pragma unroll
    for (int hc = 0; hc < 2; ++hc)
      hidf[m][hc] = *(const half8*)&hidL[rbase + m * 16][hc * 32 + q * 8];

  __syncthreads();  // ALL waves done reading hidL -> safe to overlay with bS

  // prologue: stage B tiles il=0 and il=1 into the overlay (2 x 8 KB)
  {
    const _Float16* g0 = w2pp + (size_t)cbase * 2048 + tid * 8;
    gload_lds16(g0, bSp + tid * 8);
    gload_lds16(g0 + 2048, bSp + tid * 8 + 2048);
    const _Float16* g1 = w2pp + (size_t)(cbase + 4) * 2048 + tid * 8;
    gload_lds16(g1, bSp + 4096 + tid * 8);
    gload_lds16(g1 + 2048, bSp + 4096 + tid * 8 + 2048);
  }

  floatx4 acc[2][4];
#pragma unroll
  for (int m = 0; m < 2; ++m)
#pragma unroll
    for (int og = 0; og < 4; ++og) acc[m][og] = (floatx4){0.f, 0.f, 0.f, 0.f};

  const int fbase = q * 512 + l15 * 8;  // frag base within a 2048-elem chunk

  for (int il = 0; il < 32; ++il) {
    int p = il & 1;
    _Float16 osv0 = osL[rbase][il];
    _Float16 osv1 = osL[rbase + 16][il];
    // wait for bS[p]'s DMA (own quarter), then barrier -> all quarters landed
    if (il < 31) {
      asm volatile("s_waitcnt vmcnt(2)" ::: "memory");
    } else {
      asm volatile("s_waitcnt vmcnt(0)" ::: "memory");
    }
    __builtin_amdgcn_s_barrier();
    half8 fr[2][4];
    const _Float16* bb = bSp + p * 4096;
#pragma unroll
    for (int hc = 0; hc < 2; ++hc)
#pragma unroll
      for (int og = 0; og < 4; ++og)
        fr[hc][og] = *(const half8*)&bb[hc * 2048 + fbase + og * 128];
    asm volatile("s_waitcnt lgkmcnt(0)" ::: "memory");
    __builtin_amdgcn_sched_barrier(0);
    __builtin_amdgcn_s_barrier();  // all waves done reading bS[p]
    if (il < 30) {                 // restage bS[p] with tile il+2
      const _Float16* gsrc = w2pp + (size_t)(cbase + (il + 2) * 4) * 2048 + tid * 8;
      _Float16* ldst = bSp + p * 4096 + tid * 8;
      gload_lds16(gsrc, ldst);
      gload_lds16(gsrc + 2048, ldst + 2048);
    }
    half8 os0 = {osv0, osv0, osv0, osv0, osv0, osv0, osv0, osv0};
    half8 os1 = {osv1, osv1, osv1, osv1, osv1, osv1, osv1, osv1};
#pragma unroll
    for (int hc = 0; hc < 2; ++hc) {
      half8 af0 = hidf[0][hc] * os0;
      half8 af1 = hidf[1][hc] * os1;
#pragma unroll
      for (int og = 0; og < 4; ++og) {
        acc[0][og] = __builtin_amdgcn_mfma_f32_16x16x32_f16(af0, fr[hc][og], acc[0][og], 0, 0, 0);
        acc[1][og] = __builtin_amdgcn_mfma_f32_16x16x32_f16(af1, fr[hc][og], acc[1][og], 0, 0, 0);
      }
    }
  }

  if (hb == 0) {  // bias chunk: A = os directly; i-range matches ib exactly
    int cb = 256 + ib;
    const _Float16* bp = w2pp + ((size_t)(cb * 4 + q) * 64 + l15) * 8;
    half8 af[2];
#pragma unroll
    for (int m = 0; m < 2; ++m)
      af[m] = *(const half8*)&osL[rbase + m * 16][q * 8];
#pragma unroll
    for (int og = 0; og < 4; ++og) {
      half8 bf = *(const half8*)(bp + og * 128);
#pragma unroll
      for (int m = 0; m < 2; ++m)
        acc[m][og] = __builtin_amdgcn_mfma_f32_16x16x32_f16(af[m], bf, acc[m][og], 0, 0, 0);
    }
  }

  // epilogue: C/D row=(lane>>4)*4+j (edge), col=lane&15
#pragma unroll
  for (int m = 0; m < 2; ++m) {
    int erow = e0 + wv * 32 + m * 16 + q * 4;
#pragma unroll
    for (int j = 0; j < 4; ++j) {
      int ee = erow + j;
      if (ee < NE) {
        int t = tgt[ee];
        float* ap = agg + (size_t)t * 64 + l15;
#pragma unroll
        for (int og = 0; og < 4; ++og) atomicAdd(ap + og * 16, acc[m][og][j]);
      }
    }
  }
}

// ---- GRU step via MFMA, 32 nodes/block x 128 threads (2 waves) ----
// R8 ran 235 one-block-per-CU latency chains (<1 block/CU, nothing hides the
// global->LDS->MFMA->store chain). 469 blocks of 32 nodes give ~2 blocks/CU
// and half the serial chain. Wave wv owns gate tiles g=t6*2+wv (t6<6): for
// its d-columns (wv=0: d in {0-15,32-47}; wv=1: complement) it holds complete
// (r,z,n) triples at t6 = dd, 2+dd, 4+dd where d=(dd*2+wv)*16+l15.
// Also zeroes agg in-place for the next step's atomics.
__global__ __launch_bounds__(128, 2) void k_gru(
    float* __restrict__ agg, const float* __restrict__ deg,
    const float* __restrict__ convb, const _Float16* __restrict__ wgpk,
    const float* __restrict__ bih, const float* __restrict__ bhh,
    float* __restrict__ outv) {
  __shared__ __align__(16) _Float16 aL[32][136];  // K=128 + pad8
  __shared__ float hF[32][68];
  __shared__ float cbL[64];
  int tid = threadIdx.x;
  int n0 = blockIdx.x * 32;
  if (tid < 64) cbL[tid] = convb[tid];
  __syncthreads();

  int nl = tid >> 2, dq = (tid & 3) * 16;
  int n = n0 + nl;
  if (n < NN) {
    float dg = fmaxf(deg[n], 1.f);
    const float4* ap = (const float4*)(agg + (size_t)n * 64 + dq);
    const float4* hp = (const float4*)(outv + (size_t)n * 64 + dq);
    float4* az = (float4*)(agg + (size_t)n * 64 + dq);
#pragma unroll
    for (int t = 0; t < 4; ++t) {
      float4 a = ap[t];
      float4 h = hp[t];
      int d = dq + t * 4;
      aL[nl][d + 0] = (_Float16)fmaxf(a.x / dg + cbL[d + 0], 0.f);
      aL[nl][d + 1] = (_Float16)fmaxf(a.y / dg + cbL[d + 1], 0.f);
      aL[nl][d + 2] = (_Float16)fmaxf(a.z / dg + cbL[d + 2], 0.f);
      aL[nl][d + 3] = (_Float16)fmaxf(a.w / dg + cbL[d + 3], 0.f);
      aL[nl][64 + d + 0] = (_Float16)h.x;
      aL[nl][64 + d + 1] = (_Float16)h.y;
      aL[nl][64 + d + 2] = (_Float16)h.z;
      aL[nl][64 + d + 3] = (_Float16)h.w;
      hF[nl][d + 0] = h.x; hF[nl][d + 1] = h.y;
      hF[nl][d + 2] = h.z; hF[nl][d + 3] = h.w;
      az[t] = make_float4(0.f, 0.f, 0.f, 0.f);
    }
  } else {
#pragma unroll
    for (int t = 0; t < 4; ++t) {
      int d = dq + t * 4;
#pragma unroll
      for (int u = 0; u < 4; ++u) {
        aL[nl][d + u] = (_Float16)0.f;
        aL[nl][64 + d + u] = (_Float16)0.f;
        hF[nl][d + u] = 0.f;
      }
    }
  }
  __syncthreads();

  int wv = tid >> 6, lane = tid & 63, l15 = lane & 15, qd = lane >> 4;
  floatx4 acc[2][6][2];
#pragma unroll
  for (int mt = 0; mt < 2; ++mt)
#pragma unroll
    for (int t6 = 0; t6 < 6; ++t6)
#pragma unroll
      for (int kind = 0; kind < 2; ++kind) acc[mt][t6][kind] = (floatx4){0.f, 0.f, 0.f, 0.f};

#pragma unroll
  for (int kind = 0; kind < 2; ++kind) {
#pragma unroll
    for (int cc = 0; cc < 2; ++cc) {
      half8 af[2];
#pragma unroll
      for (int mt = 0; mt < 2; ++mt)
        af[mt] = *(const half8*)&aL[mt * 16 + l15][kind * 64 + cc * 32 + qd * 8];
#pragma unroll
      for (int t6 = 0; t6 < 6; ++t6) {
        int gb = (t6 * 2 + wv) * 16;
        half8 bf = *(const half8*)&wgpk[((size_t)(kind * 2 + cc) * 192 + gb + l15) * 32 + qd * 8];
#pragma unroll
        for (int mt = 0; mt < 2; ++mt)
          acc[mt][t6][kind] = __builtin_amdgcn_mfma_f32_16x16x32_f16(af[mt], bf, acc[mt][t6][kind], 0, 0, 0);
      }
    }
  }

#pragma unroll
  for (int dd = 0; dd < 2; ++dd) {
    int d = (dd * 2 + wv) * 16 + l15;
    float bir = bih[d], bhr = bhh[d];
    float biz = bih[64 + d], bhz = bhh[64 + d];
    float bin = bih[128 + d], bhn = bhh[128 + d];
#pragma unroll
    for (int mt = 0; mt < 2; ++mt) {
#pragma unroll
      for (int j = 0; j < 4; ++j) {
        int nloc = mt * 16 + qd * 4 + j;
        int nn = n0 + nloc;
        if (nn < NN) {
          float ir = acc[mt][dd][0][j] + bir, hr = acc[mt][dd][1][j] + bhr;
          float iz = acc[mt][2 + dd][0][j] + biz, hz = acc[mt][2 + dd][1][j] + bhz;
          float in_ = acc[mt][4 + dd][0][j] + bin, hn = acc[mt][4 + dd][1][j] + bhn;
          float r = sigmoidf_(ir + hr);
          float z = sigmoidf_(iz + hz);
          float ng = tanhf(in_ + r * hn);
          float h = hF[nloc][d];
          outv[(size_t)nn * 64 + d] = (1.f - z) * ng + z * h;
        }
      }
    }
  }
}

// ---- fully fused Set2Set (6 steps) + head, one block per graph ----
__global__ __launch_bounds__(256) void k_s2s(
    const float* __restrict__ outv, const int* __restrict__ gstart,
    const int* __restrict__ gend, const float* __restrict__ wTih,
    const float* __restrict__ wThh, const float* __restrict__ bih,
    const float* __restrict__ bhh, const float* __restrict__ l1w,
    const float* __restrict__ l1b, const float* __restrict__ l2w,
    const float* __restrict__ l2b, float* __restrict__ y) {
  __shared__ float qL[128], hlL[64], clL[64], gL[256];
  __shared__ float mxA[4], smA[4], accA[4][64], hidL[64];
  int b = blockIdx.x, tid = threadIdx.x, wv = tid >> 6, lane = tid & 63;
  int s0 = gstart[b], e0 = gend[b];
  if (s0 > e0) { s0 = 0; e0 = 0; }
  if (tid < 128) qL[tid] = 0.f;
  if (tid < 64) { hlL[tid] = 0.f; clL[tid] = 0.f; }
  __syncthreads();

  for (int step = 0; step < NSTEP; ++step) {
    {  // LSTM gates, one per thread (coalesced via transposed weights)
      int g = tid;
      float s = bih[g] + bhh[g];
      for (int k = 0; k < 128; ++k) s += qL[k] * wTih[k * 256 + g];
      for (int k = 0; k < 64; ++k) s += hlL[k] * wThh[k * 256 + g];
      gL[g] = s;
    }
    __syncthreads();
    if (tid < 64) {
      float ig = gL[tid], fg = gL[64 + tid], gg = gL[128 + tid], og = gL[192 + tid];
      float c = sigmoidf_(fg) * clL[tid] + sigmoidf_(ig) * tanhf(gg);
      clL[tid] = c;
      hlL[tid] = sigmoidf_(og) * tanhf(c);
    }
    __syncthreads();
    // attention: waves split nodes strided; two passes (max, then sum/acc)
    float hd = hlL[lane];
    float mxw = -1e30f;
    for (int nn = s0 + wv; nn < e0; nn += 4) {
      float v = outv[(size_t)nn * 64 + lane] * hd;
#pragma unroll
      for (int off = 32; off > 0; off >>= 1) v += __shfl_xor(v, off);
      mxw = fmaxf(mxw, v);
    }
    if (lane == 0) mxA[wv] = mxw;
    __syncthreads();
    float mx = fmaxf(fmaxf(mxA[0], mxA[1]), fmaxf(mxA[2], mxA[3]));
    float sm = 0.f, ac = 0.f;
    for (int nn = s0 + wv; nn < e0; nn += 4) {
      float o_nd = outv[(size_t)nn * 64 + lane];
      float v = o_nd * hd;
#pragma unroll
      for (int off = 32; off > 0; off >>= 1) v += __shfl_xor(v, off);
      float ex = expf(v - mx);
      sm += ex;
      ac += ex * o_nd;
    }
    if (lane == 0) smA[wv] = sm;
    accA[wv][lane] = ac;
    __syncthreads();
    if (tid < 64) {
      float den = smA[0] + smA[1] + smA[2] + smA[3] + 1e-16f;
      float rv = (accA[0][tid] + accA[1][tid] + accA[2][tid] + accA[3][tid]) / den;
      qL[tid] = hlL[tid];
      qL[64 + tid] = rv;
    }
    __syncthreads();
  }
  // head
  if (tid < 64) {
    float s = l1b[tid];
    for (int k = 0; k < 128; ++k) s += qL[k] * l1w[tid * 128 + k];
    hidL[tid] = fmaxf(s, 0.f);
  }
  __syncthreads();
  if (tid < 12) {
    float s = l2b[tid];
    for (int k = 0; k < 64; ++k) s += hidL[k] * l2w[tid * 64 + k];
    y[b * 12 + tid] = s;
  }
}

extern "C" void kernel_launch(void* const* d_in, const int* in_sizes, int n_in,
                              void* d_out, int out_size, void* d_ws, size_t ws_size,
                              hipStream_t stream) {
  const float* x = (const float*)d_in[0];
  const float* ea = (const float*)d_in[1];
  const int* eidx = (const int*)d_in[2];
  const int* batch = (const int*)d_in[3];
  const float* lin0_w = (const float*)d_in[4];
  const float* lin0_b = (const float*)d_in[5];
  const float* en_w1 = (const float*)d_in[6];
  const float* en_b1 = (const float*)d_in[7];
  const float* en_w2 = (const float*)d_in[8];
  const float* en_b2 = (const float*)d_in[9];
  const float* conv_b = (const float*)d_in[10];
  const float* gru_wih = (const float*)d_in[11];
  const float* gru_whh = (const float*)d_in[12];
  const float* gru_bih = (const float*)d_in[13];
  const float* gru_bhh = (const float*)d_in[14];
  const float* lstm_wih = (const float*)d_in[15];
  const float* lstm_whh = (const float*)d_in[16];
  const float* lstm_bih = (const float*)d_in[17];
  const float* lstm_bhh = (const float*)d_in[18];
  const float* lin1_w = (const float*)d_in[19];
  const float* lin1_b = (const float*)d_in[20];
  const float* lin2_w = (const float*)d_in[21];
  const float* lin2_b = (const float*)d_in[22];
  const int* srcp = eidx;
  const int* tgtp = eidx + NE;

  char* ws = (char*)d_ws;
  size_t off = 0;
  auto alloc = [&](size_t bytes) {
    char* p = ws + off;
    off += (bytes + 255) & ~(size_t)255;
    return p;
  };
  _Float16* w2pp = (_Float16*)alloc((size_t)1032 * 512 * 2);  // 1.06 MB
  _Float16* wgpk = (_Float16*)alloc((size_t)24576 * 2);
  float* wTih = (float*)alloc((size_t)32768 * 4);
  float* wThh = (float*)alloc((size_t)16384 * 4);
  float* out = (float*)alloc((size_t)NN * 64 * 4);
  float* agg = (float*)alloc((size_t)NN * 64 * 4);
  float* deg = (float*)alloc((size_t)NN * 4);
  int* gstart = (int*)alloc((size_t)NB * 4);
  int* gend = (int*)alloc((size_t)NB * 4);
  if (off > ws_size) {
    k_sentinel<<<1, 1, 0, stream>>>((float*)d_out);
    return;
  }

  hipMemsetAsync(deg, 0, (size_t)NN * 4, stream);
  hipMemsetAsync(gstart, 0x7f, (size_t)NB * 4, stream);
  hipMemsetAsync(gend, 0, (size_t)NB * 4, stream);
  hipMemsetAsync(agg, 0, (size_t)NN * 64 * 4, stream);

  k_init<<<(NN * 64 + 255) / 256, 256, 0, stream>>>(
      x, lin0_w, lin0_b, tgtp, batch, out, deg, gstart, gend,
      en_w2, en_b2, gru_wih, gru_whh, lstm_wih, lstm_whh, w2pp, wgpk, wTih, wThh);

  for (int step = 0; step < NSTEP; ++step) {
    k_msg<<<dim3((NE + EPB - 1) / EPB, 4), 256, 0, stream>>>(out, ea, en_w1, en_b1,
                                                             w2pp, srcp, tgtp, agg);
    k_gru<<<(NN + 31) / 32, 128, 0, stream>>>(agg, deg, conv_b, wgpk, gru_bih,
                                              gru_bhh, out);
  }

  k_s2s<<<NB, 256, 0, stream>>>(out, gstart, gend, wTih, wThh, lstm_bih, lstm_bhh,
                                lin1_w, lin1_b, lin2_w, lin2_b, (float*)d_out);
}